// Round 4
// baseline (216.174 us; speedup 1.0000x reference)
//
#include <hip/hip_runtime.h>
#include <math.h>

#define B_ 4096
#define K_ 64
#define D_ 128

__global__ __launch_bounds__(256) void bpr_fused(
    const int* __restrict__ user, const int* __restrict__ pos,
    const int* __restrict__ negs, const float* __restrict__ uemb,
    const float* __restrict__ iemb, float* __restrict__ ws,
    unsigned* __restrict__ counter, float* __restrict__ out)
{
    const int b    = blockIdx.x;
    const int tid  = threadIdx.x;
    const int lane = tid & 63;
    const int wave = tid >> 6;
    const int g    = lane >> 3;   // 8-lane group id (0..7) -> which neg row
    const int s    = lane & 7;    // position in group -> which 64B chunk

    __shared__ float s_scores[K_];
    __shared__ float s_pos[3];     // dot_pos, sq_pos, sq_u
    __shared__ int   s_last;

    // u chunk for this lane: 16 contiguous floats at s*16 (8x redundant, L1 broadcast)
    const float* urow = uemb + (size_t)user[b] * D_;
    const float4 u0 = *reinterpret_cast<const float4*>(urow + s * 16 + 0);
    const float4 u1 = *reinterpret_cast<const float4*>(urow + s * 16 + 4);
    const float4 u2 = *reinterpret_cast<const float4*>(urow + s * 16 + 8);
    const float4 u3 = *reinterpret_cast<const float4*>(urow + s * 16 + 12);

    const int* nrow = negs + (size_t)b * K_;
    const int k0 = wave * 16 + g;
    const int k1 = k0 + 8;
    const float* nra = iemb + (size_t)nrow[k0] * D_ + s * 16;
    const float* nrb = iemb + (size_t)nrow[k1] * D_ + s * 16;

    // issue all 8 row loads back-to-back (max MLP)
    const float4 a0 = *reinterpret_cast<const float4*>(nra + 0);
    const float4 a1 = *reinterpret_cast<const float4*>(nra + 4);
    const float4 a2 = *reinterpret_cast<const float4*>(nra + 8);
    const float4 a3 = *reinterpret_cast<const float4*>(nra + 12);
    const float4 b0 = *reinterpret_cast<const float4*>(nrb + 0);
    const float4 b1 = *reinterpret_cast<const float4*>(nrb + 4);
    const float4 b2 = *reinterpret_cast<const float4*>(nrb + 8);
    const float4 b3 = *reinterpret_cast<const float4*>(nrb + 12);

    float pa0 = a0.x * u0.x + a0.y * u0.y + a0.z * u0.z + a0.w * u0.w;
    float pa1 = a1.x * u1.x + a1.y * u1.y + a1.z * u1.z + a1.w * u1.w;
    float pa2 = a2.x * u2.x + a2.y * u2.y + a2.z * u2.z + a2.w * u2.w;
    float pa3 = a3.x * u3.x + a3.y * u3.y + a3.z * u3.z + a3.w * u3.w;
    float dotA = (pa0 + pa1) + (pa2 + pa3);

    float pb0 = b0.x * u0.x + b0.y * u0.y + b0.z * u0.z + b0.w * u0.w;
    float pb1 = b1.x * u1.x + b1.y * u1.y + b1.z * u1.z + b1.w * u1.w;
    float pb2 = b2.x * u2.x + b2.y * u2.y + b2.z * u2.z + b2.w * u2.w;
    float pb3 = b3.x * u3.x + b3.y * u3.y + b3.z * u3.z + b3.w * u3.w;
    float dotB = (pb0 + pb1) + (pb2 + pb3);

    #pragma unroll
    for (int off = 4; off; off >>= 1) {     // stays within 8-lane group
        dotA += __shfl_xor(dotA, off);
        dotB += __shfl_xor(dotB, off);
    }
    if (s == 0) { s_scores[k0] = dotA; s_scores[k1] = dotB; }

    // wave 0 extra: half0 -> pos dot + pos sq ; half1 -> u sq (32-lane float4 path)
    if (wave == 0) {
        const int half = lane >> 5, sub = lane & 31;
        const float4 uv = *reinterpret_cast<const float4*>(urow + sub * 4);
        const float4 pv = *reinterpret_cast<const float4*>(
            iemb + (size_t)pos[b] * D_ + sub * 4);
        float a = half ? (uv.x * uv.x + uv.y * uv.y + uv.z * uv.z + uv.w * uv.w)
                       : (uv.x * pv.x + uv.y * pv.y + uv.z * pv.z + uv.w * pv.w);
        float c = pv.x * pv.x + pv.y * pv.y + pv.z * pv.z + pv.w * pv.w;
        #pragma unroll
        for (int off = 16; off; off >>= 1) {
            a += __shfl_xor(a, off);
            c += __shfl_xor(c, off);
        }
        if (lane == 0)  { s_pos[0] = a; s_pos[1] = c; }
        if (lane == 32) { s_pos[2] = a; }
    }
    __syncthreads();

    if (wave == 0) {
        // parallel first-occurrence argmax over 64 scores
        float v  = s_scores[lane];
        int  idx = lane;
        #pragma unroll
        for (int off = 32; off; off >>= 1) {
            const float ov = __shfl_xor(v, off);
            const int   oi = __shfl_xor(idx, off);
            if (ov > v || (ov == v && oi < idx)) { v = ov; idx = oi; }
        }
        // square-sum of the chosen negative row (L1-hot reload)
        const int nidx = nrow[idx];
        const float2 nv2 = *reinterpret_cast<const float2*>(
            iemb + (size_t)nidx * D_ + lane * 2);
        float sqn = nv2.x * nv2.x + nv2.y * nv2.y;
        #pragma unroll
        for (int off = 32; off; off >>= 1)
            sqn += __shfl_xor(sqn, off);
        if (lane == 0) {
            const float diff = s_pos[0] - v;   // pos_score - neg_score
            const float li = (diff >= 0.f) ? log1pf(expf(-diff))
                                           : (-diff + log1pf(expf(diff)));
            const float regp = s_pos[2] + s_pos[1] + sqn;
            // agent-scope stores: visible past the non-coherent per-XCD L2
            __hip_atomic_store(&ws[b],      li,   __ATOMIC_RELAXED, __HIP_MEMORY_SCOPE_AGENT);
            __hip_atomic_store(&ws[B_ + b], regp, __ATOMIC_RELAXED, __HIP_MEMORY_SCOPE_AGENT);
        }
    }

    // last-block-done: deterministic final reduce (fixed index order)
    if (tid == 0) {
        __threadfence();
        const unsigned old = __hip_atomic_fetch_add(
            counter, 1u, __ATOMIC_ACQ_REL, __HIP_MEMORY_SCOPE_AGENT);
        s_last = (old == (unsigned)(gridDim.x - 1));
    }
    __syncthreads();

    if (s_last) {
        float ls = 0.f, rs = 0.f;
        for (int i = tid; i < B_; i += 256) {
            ls += __hip_atomic_load(&ws[i],      __ATOMIC_RELAXED, __HIP_MEMORY_SCOPE_AGENT);
            rs += __hip_atomic_load(&ws[B_ + i], __ATOMIC_RELAXED, __HIP_MEMORY_SCOPE_AGENT);
        }
        #pragma unroll
        for (int off = 32; off; off >>= 1) {
            ls += __shfl_xor(ls, off);
            rs += __shfl_xor(rs, off);
        }
        __shared__ float sl[4], sr[4];
        if (lane == 0) { sl[wave] = ls; sr[wave] = rs; }
        __syncthreads();
        if (tid == 0) {
            const float L = sl[0] + sl[1] + sl[2] + sl[3];
            const float R = sr[0] + sr[1] + sr[2] + sr[3];
            out[0] = L / (float)B_;                       // loss
            out[1] = 1e-5f * 0.5f * R / (float)B_;        // reg_loss
        }
    }
}

extern "C" void kernel_launch(void* const* d_in, const int* in_sizes, int n_in,
                              void* d_out, int out_size, void* d_ws, size_t ws_size,
                              hipStream_t stream) {
    const int*   user = (const int*)  d_in[0];
    const int*   pos  = (const int*)  d_in[1];
    const int*   negs = (const int*)  d_in[2];
    const float* uemb = (const float*)d_in[3];
    const float* iemb = (const float*)d_in[4];
    float*    out     = (float*)d_out;
    float*    ws      = (float*)d_ws;
    unsigned* counter = (unsigned*)(ws + 2 * B_);

    hipMemsetAsync(counter, 0, sizeof(unsigned), stream);   // graph-capturable
    bpr_fused<<<B_, 256, 0, stream>>>(user, pos, negs, uemb, iemb, ws, counter, out);
}

// Round 5
// 30.483 us; speedup vs baseline: 7.0917x; 7.0917x over previous
//
#include <hip/hip_runtime.h>
#include <math.h>

#define B_ 4096
#define K_ 64
#define D_ 128

__global__ __launch_bounds__(256) void bpr_main(
    const int* __restrict__ user, const int* __restrict__ pos,
    const int* __restrict__ negs, const float* __restrict__ uemb,
    const float* __restrict__ iemb, float* __restrict__ ws)
{
    const int tid  = threadIdx.x;
    const int lane = tid & 63;
    const int wave = tid >> 6;
    const int g    = lane >> 3;   // 8-lane group id (0..7) -> which neg row
    const int s    = lane & 7;    // position in group -> which 64B chunk

    const int r0 = blockIdx.x * 2;      // two batch rows per block
    const int r1 = r0 + 1;

    __shared__ float s_scores[2][K_];
    __shared__ float s_pos[2][3];       // per row: dot_pos, sq_pos, sq_u

    // u chunks for both rows (8x redundant across groups, L1 broadcast)
    const float* u0row = uemb + (size_t)user[r0] * D_;
    const float* u1row = uemb + (size_t)user[r1] * D_;
    const float4 u00 = *reinterpret_cast<const float4*>(u0row + s * 16 + 0);
    const float4 u01 = *reinterpret_cast<const float4*>(u0row + s * 16 + 4);
    const float4 u02 = *reinterpret_cast<const float4*>(u0row + s * 16 + 8);
    const float4 u03 = *reinterpret_cast<const float4*>(u0row + s * 16 + 12);
    const float4 u10 = *reinterpret_cast<const float4*>(u1row + s * 16 + 0);
    const float4 u11 = *reinterpret_cast<const float4*>(u1row + s * 16 + 4);
    const float4 u12 = *reinterpret_cast<const float4*>(u1row + s * 16 + 8);
    const float4 u13 = *reinterpret_cast<const float4*>(u1row + s * 16 + 12);

    const int* nrow0 = negs + (size_t)r0 * K_;
    const int* nrow1 = negs + (size_t)r1 * K_;
    const int k0 = wave * 16 + g;
    const int k1 = k0 + 8;

    const float* pa = iemb + (size_t)nrow0[k0] * D_ + s * 16;
    const float* pb = iemb + (size_t)nrow0[k1] * D_ + s * 16;
    const float* pc = iemb + (size_t)nrow1[k0] * D_ + s * 16;
    const float* pd = iemb + (size_t)nrow1[k1] * D_ + s * 16;

    // 16 independent 16B loads in flight per lane
    const float4 a0 = *reinterpret_cast<const float4*>(pa + 0);
    const float4 a1 = *reinterpret_cast<const float4*>(pa + 4);
    const float4 a2 = *reinterpret_cast<const float4*>(pa + 8);
    const float4 a3 = *reinterpret_cast<const float4*>(pa + 12);
    const float4 b0 = *reinterpret_cast<const float4*>(pb + 0);
    const float4 b1 = *reinterpret_cast<const float4*>(pb + 4);
    const float4 b2 = *reinterpret_cast<const float4*>(pb + 8);
    const float4 b3 = *reinterpret_cast<const float4*>(pb + 12);
    const float4 c0 = *reinterpret_cast<const float4*>(pc + 0);
    const float4 c1 = *reinterpret_cast<const float4*>(pc + 4);
    const float4 c2 = *reinterpret_cast<const float4*>(pc + 8);
    const float4 c3 = *reinterpret_cast<const float4*>(pc + 12);
    const float4 d0 = *reinterpret_cast<const float4*>(pd + 0);
    const float4 d1 = *reinterpret_cast<const float4*>(pd + 4);
    const float4 d2 = *reinterpret_cast<const float4*>(pd + 8);
    const float4 d3 = *reinterpret_cast<const float4*>(pd + 12);

    float dotA = (a0.x*u00.x + a0.y*u00.y + a0.z*u00.z + a0.w*u00.w)
               + (a1.x*u01.x + a1.y*u01.y + a1.z*u01.z + a1.w*u01.w)
               + (a2.x*u02.x + a2.y*u02.y + a2.z*u02.z + a2.w*u02.w)
               + (a3.x*u03.x + a3.y*u03.y + a3.z*u03.z + a3.w*u03.w);
    float dotB = (b0.x*u00.x + b0.y*u00.y + b0.z*u00.z + b0.w*u00.w)
               + (b1.x*u01.x + b1.y*u01.y + b1.z*u01.z + b1.w*u01.w)
               + (b2.x*u02.x + b2.y*u02.y + b2.z*u02.z + b2.w*u02.w)
               + (b3.x*u03.x + b3.y*u03.y + b3.z*u03.z + b3.w*u03.w);
    float dotC = (c0.x*u10.x + c0.y*u10.y + c0.z*u10.z + c0.w*u10.w)
               + (c1.x*u11.x + c1.y*u11.y + c1.z*u11.z + c1.w*u11.w)
               + (c2.x*u12.x + c2.y*u12.y + c2.z*u12.z + c2.w*u12.w)
               + (c3.x*u13.x + c3.y*u13.y + c3.z*u13.z + c3.w*u13.w);
    float dotD = (d0.x*u10.x + d0.y*u10.y + d0.z*u10.z + d0.w*u10.w)
               + (d1.x*u11.x + d1.y*u11.y + d1.z*u11.z + d1.w*u11.w)
               + (d2.x*u12.x + d2.y*u12.y + d2.z*u12.z + d2.w*u12.w)
               + (d3.x*u13.x + d3.y*u13.y + d3.z*u13.z + d3.w*u13.w);

    #pragma unroll
    for (int off = 4; off; off >>= 1) {     // stays within 8-lane group
        dotA += __shfl_xor(dotA, off);
        dotB += __shfl_xor(dotB, off);
        dotC += __shfl_xor(dotC, off);
        dotD += __shfl_xor(dotD, off);
    }
    if (s == 0) {
        s_scores[0][k0] = dotA; s_scores[0][k1] = dotB;
        s_scores[1][k0] = dotC; s_scores[1][k1] = dotD;
    }

    // waves 0/1: pos dot + pos sq + u sq for rows 0/1 (32-lane float4 path)
    if (wave < 2) {
        const int row  = wave;
        const int ridx = r0 + row;
        const int half = lane >> 5, sub = lane & 31;
        const float* ur = row ? u1row : u0row;
        const float4 uv = *reinterpret_cast<const float4*>(ur + sub * 4);
        const float4 pv = *reinterpret_cast<const float4*>(
            iemb + (size_t)pos[ridx] * D_ + sub * 4);
        float a = half ? (uv.x*uv.x + uv.y*uv.y + uv.z*uv.z + uv.w*uv.w)
                       : (uv.x*pv.x + uv.y*pv.y + uv.z*pv.z + uv.w*pv.w);
        float c = pv.x*pv.x + pv.y*pv.y + pv.z*pv.z + pv.w*pv.w;
        #pragma unroll
        for (int off = 16; off; off >>= 1) {
            a += __shfl_xor(a, off);
            c += __shfl_xor(c, off);
        }
        if (lane == 0)  { s_pos[row][0] = a; s_pos[row][1] = c; }
        if (lane == 32) { s_pos[row][2] = a; }
    }
    __syncthreads();

    // waves 0/1: argmax + tail for rows 0/1 in parallel
    if (wave < 2) {
        const int row  = wave;
        const int ridx = r0 + row;
        float v  = s_scores[row][lane];
        int  idx = lane;
        #pragma unroll
        for (int off = 32; off; off >>= 1) {
            const float ov = __shfl_xor(v, off);
            const int   oi = __shfl_xor(idx, off);
            if (ov > v || (ov == v && oi < idx)) { v = ov; idx = oi; }
        }
        // square-sum of the chosen negative row (L1-hot reload)
        const int nidx = (row ? nrow1 : nrow0)[idx];
        const float2 nv2 = *reinterpret_cast<const float2*>(
            iemb + (size_t)nidx * D_ + lane * 2);
        float sqn = nv2.x * nv2.x + nv2.y * nv2.y;
        #pragma unroll
        for (int off = 32; off; off >>= 1)
            sqn += __shfl_xor(sqn, off);
        if (lane == 0) {
            const float diff = s_pos[row][0] - v;   // pos_score - neg_score
            const float li = (diff >= 0.f) ? log1pf(expf(-diff))
                                           : (-diff + log1pf(expf(diff)));
            ws[ridx]      = li;
            ws[B_ + ridx] = s_pos[row][2] + s_pos[row][1] + sqn;
        }
    }
}

__global__ __launch_bounds__(1024) void bpr_reduce(
    const float* __restrict__ ws, float* __restrict__ out)
{
    const int tid = threadIdx.x;            // 1024 threads, one float4 each
    const float4 l4 = reinterpret_cast<const float4*>(ws)[tid];
    const float4 r4 = reinterpret_cast<const float4*>(ws + B_)[tid];
    float ls = (l4.x + l4.y) + (l4.z + l4.w);
    float rs = (r4.x + r4.y) + (r4.z + r4.w);
    #pragma unroll
    for (int off = 32; off; off >>= 1) {
        ls += __shfl_xor(ls, off);
        rs += __shfl_xor(rs, off);
    }
    __shared__ float sl[16], sr[16];
    const int lane = tid & 63, wave = tid >> 6;
    if (lane == 0) { sl[wave] = ls; sr[wave] = rs; }
    __syncthreads();
    if (tid == 0) {
        float L = 0.f, R = 0.f;
        #pragma unroll
        for (int w = 0; w < 16; ++w) { L += sl[w]; R += sr[w]; }
        out[0] = L / (float)B_;                       // loss
        out[1] = 1e-5f * 0.5f * R / (float)B_;        // reg_loss
    }
}

extern "C" void kernel_launch(void* const* d_in, const int* in_sizes, int n_in,
                              void* d_out, int out_size, void* d_ws, size_t ws_size,
                              hipStream_t stream) {
    const int*   user = (const int*)  d_in[0];
    const int*   pos  = (const int*)  d_in[1];
    const int*   negs = (const int*)  d_in[2];
    const float* uemb = (const float*)d_in[3];
    const float* iemb = (const float*)d_in[4];
    float* out = (float*)d_out;
    float* ws  = (float*)d_ws;

    bpr_main<<<B_ / 2, 256, 0, stream>>>(user, pos, negs, uemb, iemb, ws);
    bpr_reduce<<<1, 1024, 0, stream>>>(ws, out);
}